// Round 1
// baseline (143.248 us; speedup 1.0000x reference)
//
#include <hip/hip_runtime.h>

// VectorQuantizer gather: out[b][d][n] = embedding[indices[b][n]][d]
// B=32, N=4096 (64x64), K=1024, D=256. fp32 out = 128 MiB -> write-BW bound.
//
// Design:
//  - 2048 blocks x 256 threads. Block = (b, 64-wide n-tile), covers all 256 d.
//  - lane l <-> n (stores coalesced along n, 64x4B = 256B contiguous / instr)
//  - each lane float4-gathers 16B of its (random) embedding row per iter:
//    4x fewer scattered transactions than scalar gathers.
//  - chunk c = 4*i + w (w = wave id): the 4 waves of a block touch the same
//    64B line of each row at the same iteration -> L1 line fetched once, hit 3x.
//  - index loaded once per thread, held in register for all 16 iterations.
//  - no LDS (column reads through LDS would eat 4-8 way bank conflicts).

#define VQ_B 32
#define VQ_N 4096
#define VQ_D 256

__global__ __launch_bounds__(256) void vq_gather_kernel(
    const int* __restrict__ indices,
    const float* __restrict__ embedding,
    float* __restrict__ out)
{
    const int bid = blockIdx.x;
    const int b  = bid >> 6;           // 0..31
    const int n0 = (bid & 63) << 6;    // n-tile base, 0..4032
    const int l  = threadIdx.x & 63;   // lane <-> n offset
    const int w  = threadIdx.x >> 6;   // wave id 0..3 <-> d-chunk phase

    const int n   = n0 + l;
    const int idx = indices[b * VQ_N + n];
    const float4* __restrict__ row = (const float4*)(embedding + idx * VQ_D);

    // out linear index fits in int32: max ~33.5M < 2^31
    const int out_base = b * (VQ_D * VQ_N) + n;

    #pragma unroll
    for (int i = 0; i < 16; ++i) {
        const int c = i * 4 + w;       // float4 chunk 0..63 within the row
        const float4 v = row[c];
        const int d = c << 2;
        out[out_base + (d + 0) * VQ_N] = v.x;
        out[out_base + (d + 1) * VQ_N] = v.y;
        out[out_base + (d + 2) * VQ_N] = v.z;
        out[out_base + (d + 3) * VQ_N] = v.w;
    }
}

extern "C" void kernel_launch(void* const* d_in, const int* in_sizes, int n_in,
                              void* d_out, int out_size, void* d_ws, size_t ws_size,
                              hipStream_t stream) {
    const int*   indices   = (const int*)d_in[0];    // (32,1,4096) int
    const float* embedding = (const float*)d_in[1];  // (1024,256) fp32
    // d_in[2], d_in[3] are h=64, w=64 scalars -- compile-time constants here.
    float* out = (float*)d_out;                      // (32,256,64,64) fp32

    vq_gather_kernel<<<dim3(VQ_B * (VQ_N / 64)), dim3(256), 0, stream>>>(
        indices, embedding, out);
}